// Round 5
// baseline (385.942 us; speedup 1.0000x reference)
//
#include <hip/hip_runtime.h>
#include <hip/hip_bf16.h>

#define BDIM 8
#define NTOK 8192
#define CDIM 256
#define HEADS 4
#define DHEAD 64
#define MROWS (BDIM * NTOK)   // 65536
#define WS_STRIDE 264         // padded k-stride (ushorts) for the 128x256 B tile
#define TS_STRIDE 136         // transpose buffer m-stride (16B-aligned rows)

typedef unsigned short ushort_t;
typedef short bf16x8 __attribute__((ext_vector_type(8)));
typedef float f32x4 __attribute__((ext_vector_type(4)));
typedef unsigned short u16x8 __attribute__((ext_vector_type(8)));
typedef unsigned short u16x4 __attribute__((ext_vector_type(4)));

__device__ inline ushort_t f2bf(float f) {
    __hip_bfloat16 h = __float2bfloat16(f);
    return *reinterpret_cast<ushort_t*>(&h);
}

__device__ inline bf16x8 pack8(float4 a, float4 b) {
    bf16x8 o;
    o[0] = (short)f2bf(a.x); o[1] = (short)f2bf(a.y);
    o[2] = (short)f2bf(a.z); o[3] = (short)f2bf(a.w);
    o[4] = (short)f2bf(b.x); o[5] = (short)f2bf(b.y);
    o[6] = (short)f2bf(b.z); o[7] = (short)f2bf(b.w);
    return o;
}

// ---------------------------------------------------------------------------
__global__ __launch_bounds__(256) void zero_kernel(float* __restrict__ p, int n) {
    int i = blockIdx.x * 256 + threadIdx.x;
    if (i < n) p[i] = 0.0f;
}

// ---------------------------------------------------------------------------
// Convert Wq|Wk|Wv fp32 -> bf16 into flat Wb3 (3 x 65536).
__global__ __launch_bounds__(256) void cvt_w(
    const float* __restrict__ Wq, const float* __restrict__ Wk,
    const float* __restrict__ Wv, ushort_t* __restrict__ Wb3)
{
    int i = (blockIdx.x * 256 + threadIdx.x) * 8;   // grid 96 -> 196608
    const float* s; int off;
    if (i < 65536)       { s = Wq; off = i; }
    else if (i < 131072) { s = Wk; off = i - 65536; }
    else                 { s = Wv; off = i - 131072; }
    float4 a = *(const float4*)&s[off];
    float4 b = *(const float4*)&s[off + 4];
    *(bf16x8*)&Wb3[i] = pack8(a, b);
}

// ---------------------------------------------------------------------------
// Barrier-free projection GEMM. Grid (6, 512): x -> (z = x>>1, c0 = (x&1)*128),
// y -> m-tile (128 rows). Weight c-tile (128x256 bf16) preloaded to LDS ONCE;
// K-loop has NO barriers: A-frags read fp32 from global, cvt in-reg, waves
// slip freely. z=0: q -> qT (transposed [bh][d][n]) + ssq; z=1: k -> kT + ssk;
// z=2: v -> vp (normal [n][c]).
__global__ __launch_bounds__(256, 2) void proj_direct(
    const float* __restrict__ x1, const float* __restrict__ x2,
    const ushort_t* __restrict__ Wb3,
    ushort_t* __restrict__ qT, ushort_t* __restrict__ kT,
    ushort_t* __restrict__ vp,
    float* __restrict__ ssq, float* __restrict__ ssk)
{
    __shared__ ushort_t Ws[128 * WS_STRIDE];   // 66 KB: weight tile, reused as transpose buf
    __shared__ float colss[128];

    const int t = threadIdx.x;
    const int lane = t & 63, w = t >> 6;
    const int l16 = lane & 15, quad = lane >> 4;
    const int zc = blockIdx.x;             // 0..5
    const int z = zc >> 1, c0 = (zc & 1) * 128;
    const int m0 = blockIdx.y * 128;
    const int b = m0 >> 13;                // 128-row tile never crosses a batch
    const int nloc = m0 & (NTOK - 1);      // batch-local token offset (R4 bug fix)

    const float* A = (z == 0) ? x1 : x2;
    const ushort_t* W = Wb3 + z * 65536;

    // stage weight tile: row c (bf16), padded stride
    {
        const int c = t >> 1, kh = t & 1;
        const ushort_t* src = W + (size_t)(c0 + c) * CDIM + kh * 128;
        ushort_t* dst = &Ws[c * WS_STRIDE + kh * 128];
#pragma unroll
        for (int r = 0; r < 16; ++r)
            *(u16x8*)&dst[r * 8] = *(const u16x8*)&src[r * 8];
    }
    __syncthreads();

    const int wm = w * 32;
    const size_t arow0 = (size_t)(m0 + wm + l16) * CDIM;

    f32x4 acc[2][8] = {};

#pragma unroll 2
    for (int it = 0; it < 8; ++it) {
        const int kk = it * 32 + quad * 8;
        bf16x8 aF[2];
#pragma unroll
        for (int i = 0; i < 2; ++i) {
            float4 lo = *(const float4*)&A[arow0 + (size_t)i * 16 * CDIM + kk];
            float4 hi = *(const float4*)&A[arow0 + (size_t)i * 16 * CDIM + kk + 4];
            aF[i] = pack8(lo, hi);
        }
        bf16x8 bF[8];
#pragma unroll
        for (int j = 0; j < 8; ++j)
            bF[j] = *(const bf16x8*)&Ws[(j * 16 + l16) * WS_STRIDE + kk];
#pragma unroll
        for (int i = 0; i < 2; ++i)
#pragma unroll
            for (int j = 0; j < 8; ++j)
                acc[i][j] = __builtin_amdgcn_mfma_f32_16x16x32_bf16(aF[i], bF[j], acc[i][j], 0, 0, 0);
    }

    if (z == 2) {
        // v: normal [n][c] bf16 store (C/D layout: col=l16, row=quad*4+reg)
#pragma unroll
        for (int i = 0; i < 2; ++i)
#pragma unroll
            for (int j = 0; j < 8; ++j) {
                int colg = c0 + j * 16 + l16;
#pragma unroll
                for (int reg = 0; reg < 4; ++reg) {
                    int row = m0 + wm + i * 16 + quad * 4 + reg;
                    vp[(size_t)row * CDIM + colg] = f2bf(acc[i][j][reg]);
                }
            }
        return;
    }

    float* ss = (z == 0) ? ssq : ssk;
    ushort_t* T = (z == 0) ? qT : kT;

    __syncthreads();                  // all waves done reading Ws
    if (t < 128) colss[t] = 0.0f;
    ushort_t* Ts = Ws;                // reuse as [c][m] transpose buffer, stride TS_STRIDE
#pragma unroll
    for (int i = 0; i < 2; ++i)
#pragma unroll
        for (int j = 0; j < 8; ++j) {
            u16x4 p;
            p[0] = f2bf(acc[i][j][0]); p[1] = f2bf(acc[i][j][1]);
            p[2] = f2bf(acc[i][j][2]); p[3] = f2bf(acc[i][j][3]);
            *(u16x4*)&Ts[(j * 16 + l16) * TS_STRIDE + wm + i * 16 + quad * 4] = p;
        }
    __syncthreads();

    // column sum-of-squares from registers
#pragma unroll
    for (int j = 0; j < 8; ++j) {
        float s = 0.0f;
#pragma unroll
        for (int i = 0; i < 2; ++i)
#pragma unroll
            for (int reg = 0; reg < 4; ++reg)
                s += acc[i][j][reg] * acc[i][j][reg];
        atomicAdd(&colss[j * 16 + l16], s);
    }

    // transposed coalesced store: qT[((b*H+h)*64+d)][nloc..]
    {
        const int r = t >> 1, mh = t & 1;
        const int cg = c0 + r;
        const int h = cg >> 6, d = cg & 63;
        ushort_t* dst = T + ((size_t)(b * HEADS + h) * 64 + d) * NTOK + nloc + mh * 64;
#pragma unroll
        for (int u = 0; u < 8; ++u)
            *(u16x8*)&dst[u * 8] = *(const u16x8*)&Ts[r * TS_STRIDE + mh * 64 + u * 8];
    }
    __syncthreads();
    if (t < 128) atomicAdd(&ss[b * CDIM + c0 + t], colss[t]);
}

// ---------------------------------------------------------------------------
// Gram from transposed q/k: no LDS staging, fragments direct from global.
// Grid (16 slabs, 32 bh). Wave w covers n-chunks slab*512 + r*128 + w*32.
__global__ __launch_bounds__(256) void gram_direct(
    const ushort_t* __restrict__ qT, const ushort_t* __restrict__ kT,
    float* __restrict__ G)
{
    __shared__ float gsum[4096];

    const int t = threadIdx.x;
    const int lane = t & 63, w = t >> 6;
    const int l16 = lane & 15, quad = lane >> 4;
    const int slab = blockIdx.x, bh = blockIdx.y;
    const ushort_t* Qb = qT + (size_t)bh * 64 * NTOK;
    const ushort_t* Kb = kT + (size_t)bh * 64 * NTOK;

    for (int i = t; i < 4096; i += 256) gsum[i] = 0.0f;

    f32x4 acc[4][4] = {};

#pragma unroll
    for (int r = 0; r < 4; ++r) {
        const int n_off = slab * 512 + r * 128 + w * 32 + quad * 8;
        bf16x8 aF[4], bF[4];
#pragma unroll
        for (int i = 0; i < 4; ++i)
            aF[i] = *(const bf16x8*)&Qb[(size_t)(i * 16 + l16) * NTOK + n_off];
#pragma unroll
        for (int j = 0; j < 4; ++j)
            bF[j] = *(const bf16x8*)&Kb[(size_t)(j * 16 + l16) * NTOK + n_off];
#pragma unroll
        for (int i = 0; i < 4; ++i)
#pragma unroll
            for (int j = 0; j < 4; ++j)
                acc[i][j] = __builtin_amdgcn_mfma_f32_16x16x32_bf16(aF[i], bF[j], acc[i][j], 0, 0, 0);
    }

    __syncthreads();
#pragma unroll
    for (int i = 0; i < 4; ++i)
#pragma unroll
        for (int j = 0; j < 4; ++j)
#pragma unroll
            for (int reg = 0; reg < 4; ++reg)
                atomicAdd(&gsum[(i * 16 + quad * 4 + reg) * 64 + j * 16 + l16], acc[i][j][reg]);
    __syncthreads();

    float* Gp = G + (size_t)bh * 4096;
    for (int i = t; i < 4096; i += 256) atomicAdd(&Gp[i], gsum[i]);
}

// ---------------------------------------------------------------------------
// normalize by L2 norms (clamped), temperature, row softmax
__global__ __launch_bounds__(64) void attn_softmax(
    float* __restrict__ G, const float* __restrict__ ssq,
    const float* __restrict__ ssk, const float* __restrict__ temp)
{
    const int h = blockIdx.x, b = blockIdx.y;
    const int d = threadIdx.x;
    __shared__ float nk[64];

    float nq = fmaxf(sqrtf(ssq[b * CDIM + h * DHEAD + d]), 1e-12f);
    nk[d]    = fmaxf(sqrtf(ssk[b * CDIM + h * DHEAD + d]), 1e-12f);
    __syncthreads();

    float* row = G + (size_t)(b * HEADS + h) * DHEAD * DHEAD + d * DHEAD;
    const float tmp = temp[h];

    float vals[64];
    float mx = -1e30f;
#pragma unroll
    for (int e = 0; e < 64; ++e) {
        float v = row[e] / (nq * nk[e]) * tmp;
        vals[e] = v;
        mx = fmaxf(mx, v);
    }
    float s = 0.0f;
#pragma unroll
    for (int e = 0; e < 64; ++e) {
        float ev = __expf(vals[e] - mx);
        vals[e] = ev;
        s += ev;
    }
    float inv = 1.0f / s;
#pragma unroll
    for (int e = 0; e < 64; ++e) row[e] = vals[e] * inv;
}

// ---------------------------------------------------------------------------
// W_eff[b][c][h*64+e] = sum_d Wo[c][h*64+d] * attn[b][h][d][e], bf16 out
__global__ __launch_bounds__(256) void weff_kernel(
    const float* __restrict__ Wo, const float* __restrict__ attn,
    ushort_t* __restrict__ Weffb)
{
    const int h = blockIdx.x, b = blockIdx.y;
    const int c = threadIdx.x;
    __shared__ float at[64][65];

    const float* Ab = attn + (size_t)(b * HEADS + h) * DHEAD * DHEAD;
    for (int idx = c; idx < DHEAD * DHEAD; idx += 256)
        at[idx >> 6][idx & 63] = Ab[idx];
    __syncthreads();

    float wo[64];
#pragma unroll
    for (int d2 = 0; d2 < 64; ++d2) wo[d2] = Wo[(size_t)c * CDIM + h * DHEAD + d2];

    ushort_t* Wb = Weffb + (size_t)b * CDIM * CDIM + (size_t)c * CDIM + h * DHEAD;
#pragma unroll 4
    for (int e = 0; e < 64; ++e) {
        float s = 0.0f;
#pragma unroll
        for (int d2 = 0; d2 < 64; ++d2) s += wo[d2] * at[d2][e];
        Wb[e] = f2bf(s);
    }
}

// ---------------------------------------------------------------------------
// Barrier-free output GEMM: out[m][c] = bo[c] + sum_k vp[m][k]*Weff[b][c][k].
// Grid (2, 512): x -> c-tile, y -> m-tile. Weff c-tile preloaded once.
__global__ __launch_bounds__(256, 2) void out_direct(
    const ushort_t* __restrict__ vp, const ushort_t* __restrict__ Weffb,
    const float* __restrict__ bo, float* __restrict__ out)
{
    __shared__ ushort_t Ws[128 * WS_STRIDE];

    const int t = threadIdx.x;
    const int lane = t & 63, w = t >> 6;
    const int l16 = lane & 15, quad = lane >> 4;
    const int c0 = blockIdx.x * 128;
    const int m0 = blockIdx.y * 128;
    const int b = m0 >> 13;
    const ushort_t* Wb = Weffb + (size_t)b * CDIM * CDIM;

    {
        const int c = t >> 1, kh = t & 1;
        const ushort_t* src = Wb + (size_t)(c0 + c) * CDIM + kh * 128;
        ushort_t* dst = &Ws[c * WS_STRIDE + kh * 128];
#pragma unroll
        for (int r = 0; r < 16; ++r)
            *(u16x8*)&dst[r * 8] = *(const u16x8*)&src[r * 8];
    }
    __syncthreads();

    const int wm = w * 32;
    const size_t arow0 = (size_t)(m0 + wm + l16) * CDIM;

    f32x4 acc[2][8] = {};

#pragma unroll 2
    for (int it = 0; it < 8; ++it) {
        const int kk = it * 32 + quad * 8;
        bf16x8 aF[2];
#pragma unroll
        for (int i = 0; i < 2; ++i)
            aF[i] = *(const bf16x8*)&vp[arow0 + (size_t)i * 16 * CDIM + kk];
        bf16x8 bF[8];
#pragma unroll
        for (int j = 0; j < 8; ++j)
            bF[j] = *(const bf16x8*)&Ws[(j * 16 + l16) * WS_STRIDE + kk];
#pragma unroll
        for (int i = 0; i < 2; ++i)
#pragma unroll
            for (int j = 0; j < 8; ++j)
                acc[i][j] = __builtin_amdgcn_mfma_f32_16x16x32_bf16(aF[i], bF[j], acc[i][j], 0, 0, 0);
    }

#pragma unroll
    for (int i = 0; i < 2; ++i)
#pragma unroll
        for (int j = 0; j < 8; ++j) {
            int colg = c0 + j * 16 + l16;
            float bias = bo[colg];
#pragma unroll
            for (int reg = 0; reg < 4; ++reg) {
                int row = m0 + wm + i * 16 + quad * 4 + reg;
                out[(size_t)row * CDIM + colg] = acc[i][j][reg] + bias;
            }
        }
}

// ---------------------------------------------------------------------------
extern "C" void kernel_launch(void* const* d_in, const int* in_sizes, int n_in,
                              void* d_out, int out_size, void* d_ws, size_t ws_size,
                              hipStream_t stream) {
    const float* x1   = (const float*)d_in[0];
    const float* x2   = (const float*)d_in[1];
    const float* Wq   = (const float*)d_in[2];
    const float* Wk   = (const float*)d_in[3];
    const float* Wv   = (const float*)d_in[4];
    const float* Wo   = (const float*)d_in[5];
    const float* bo   = (const float*)d_in[6];
    const float* temp = (const float*)d_in[7];
    float* out = (float*)d_out;

    char* ws = (char*)d_ws;
    const size_t SZP = (size_t)MROWS * CDIM * sizeof(ushort_t);   // 32 MB
    ushort_t* qT   = (ushort_t*)(ws);
    ushort_t* kT   = (ushort_t*)(ws + SZP);
    ushort_t* vp   = (ushort_t*)(ws + 2 * SZP);
    float*    ssq  = (float*)(ws + 3 * SZP);                  // 8 KB
    float*    ssk  = (float*)(ws + 3 * SZP + 8192);           // 8 KB
    float*    G    = (float*)(ws + 3 * SZP + 16384);          // 512 KB
    ushort_t* Weffb= (ushort_t*)(ws + 3 * SZP + 540672);      // 1 MB
    ushort_t* Wb3  = (ushort_t*)(ws + 3 * SZP + 1589248);     // 384 KB

    // zero ssq+ssk+G (contiguous, 135168 floats)
    zero_kernel<<<dim3((135168 + 255) / 256), dim3(256), 0, stream>>>(ssq, 135168);

    cvt_w<<<dim3(96), dim3(256), 0, stream>>>(Wq, Wk, Wv, Wb3);

    proj_direct<<<dim3(6, 512), dim3(256), 0, stream>>>(
        x1, x2, Wb3, qT, kT, vp, ssq, ssk);

    gram_direct<<<dim3(16, 32), dim3(256), 0, stream>>>(qT, kT, G);

    attn_softmax<<<dim3(HEADS, BDIM), dim3(64), 0, stream>>>(G, ssq, ssk, temp);

    weff_kernel<<<dim3(HEADS, BDIM), dim3(256), 0, stream>>>(Wo, G, Weffb);

    out_direct<<<dim3(2, 512), dim3(256), 0, stream>>>(vp, Weffb, bo, out);
}